// Round 1
// baseline (8444.603 us; speedup 1.0000x reference)
//
#include <hip/hip_runtime.h>
#include <hip/hip_bf16.h>

#define T_STEPS 512
#define D_IN 75
#define H_DIM 512
#define G_DIM 2048
#define NCLS_ 11
#define NKK 19           // 16 h-ktiles + 3 x-ktiles (K = 512 + 96pad = 608)
#define NG 8             // batch groups (32 rows each)
#define NJ 16            // column groups (32 h-cols each)

typedef __attribute__((ext_vector_type(8))) short short8;
typedef __attribute__((ext_vector_type(4))) float f32x4;

__device__ __forceinline__ unsigned short f2b(float f) {
  unsigned int u = __float_as_uint(f);
  unsigned int r = (u + 0x7fffu + ((u >> 16) & 1u)) >> 16;
  return (unsigned short)r;
}
__device__ __forceinline__ float b2f(unsigned short u) {
  return __uint_as_float(((unsigned int)u) << 16);
}
__device__ __forceinline__ float softplusf(float v) {
  return (v > 20.f) ? v : log1pf(__expf(v));
}
__device__ __forceinline__ float sigmf(float v) {
  return 1.f / (1.f + __expf(-v));
}
__device__ __forceinline__ float tanhf_(float v) {
  float a = fabsf(v);
  float e = __expf(-2.f * a);
  float r = (1.f - e) / (1.f + e);
  return copysignf(r, v);
}
__device__ __forceinline__ unsigned long long pack4(const unsigned short* v) {
  return (unsigned long long)v[0] | ((unsigned long long)v[1] << 16) |
         ((unsigned long long)v[2] << 32) | ((unsigned long long)v[3] << 48);
}

// ---------------------------------------------------------------------------
// Prologue: sample W = mu + softplus(rho)*eps for [w_hh; w_ih; 0pad] (608 x 2048)
// and pack into MFMA B-fragment chunks.
// Chunk c = (j*8 + w)*19 + kk ; element (lane l, e):
//   k = kk*32 + (l>>4)*8 + e
//   n = 512*q + j*32 + w*4 + cc   with  s=l&15, q=s>>2, cc=s&3
// ---------------------------------------------------------------------------
__global__ __launch_bounds__(64) void pack_w_kernel(
    const float* __restrict__ wih_mu, const float* __restrict__ wih_rho, const float* __restrict__ eps_ih,
    const float* __restrict__ whh_mu, const float* __restrict__ whh_rho, const float* __restrict__ eps_hh,
    unsigned short* __restrict__ wpack)
{
  int c = blockIdx.x;             // 0..2431
  int j = c / (8 * NKK);
  int r = c % (8 * NKK);
  int w = r / NKK;
  int kk = r % NKK;
  int l = threadIdx.x;
  int s = l & 15, grp = l >> 4;
  int q = s >> 2, cc = s & 3;
  int n = q * 512 + j * 32 + w * 4 + cc;
  unsigned short vs[8];
#pragma unroll
  for (int e = 0; e < 8; ++e) {
    int k = kk * 32 + grp * 8 + e;
    float val = 0.f;
    if (k < 512) {
      int idx = k * G_DIM + n;
      val = whh_mu[idx] + softplusf(whh_rho[idx]) * eps_hh[idx];
    } else if (k < 512 + D_IN) {
      int idx = (k - 512) * G_DIM + n;
      val = wih_mu[idx] + softplusf(wih_rho[idx]) * eps_ih[idx];
    }
    vs[e] = f2b(val);
  }
  unsigned long long u0 = pack4(vs);
  unsigned long long u1 = pack4(vs + 4);
  unsigned long long* dst = (unsigned long long*)wpack + (size_t)c * 128 + l * 2;
  dst[0] = u0;
  dst[1] = u1;
}

// ---------------------------------------------------------------------------
// Persistent scan kernel. 128 blocks = 8 batch-groups x 16 col-groups.
// Block (g,j): rows [g*32, g*32+32), h-cols [j*32, j*32+32).
// Wave w owns h-cols j*32 + 4w + {0..3} via one mixed i/f/g/o 16x16 tile,
// two row-groups (rg) of 16 rows. W slice lives in 19 short8 VGPRs.
// Per step: spin on group flags, load h fragments (agent-scope, LLC),
// 38 MFMA, LDS-transpose epilogue, publish own h chunk + flag.
// ---------------------------------------------------------------------------
struct SmemLoop {
  float gatesT[8][2][16][16];        // 16KB [wave][rg][slot][row]
  unsigned short h_lds[2][32][32];   // 4KB
  unsigned short x_lds[2][6][64][8]; // 12KB [buf][rg*3+kx][lane][e]
};
union Smem {
  SmemLoop s;
  unsigned short zbuf[32][512];      // 32KB (post-loop only)
};

__global__ __launch_bounds__(512, 2) void lstm_scan_kernel(
    const float* __restrict__ x,
    const unsigned short* __restrict__ wpack,
    const float* __restrict__ b_mu, const float* __restrict__ b_rho, const float* __restrict__ eps_b,
    const float* __restrict__ fc_w, const float* __restrict__ fc_b,
    unsigned long long* __restrict__ hbuf, int* __restrict__ flags,
    float* __restrict__ out)
{
  __shared__ Smem sm;

  const int bid = blockIdx.x;
  const int g = bid >> 4, j = bid & 15;
  const int tid = threadIdx.x;
  const int w = tid >> 6, lane = tid & 63;
  const int srow = lane & 15, grp = lane >> 4;

  // ---- load stationary W fragments (19 x 16B per lane)
  short8 Wreg[NKK];
  {
    const short8* wp = (const short8*)wpack;
    const int cj = (j * 8 + w) * NKK;
#pragma unroll
    for (int kk = 0; kk < NKK; ++kk)
      Wreg[kk] = wp[(size_t)(cj + kk) * 64 + lane];
  }
  // ---- sampled bias (per-lane constants; epilogue lane role: row=srow, cc=grp)
  float bias_[4];
#pragma unroll
  for (int q = 0; q < 4; ++q) {
    int idx = q * 512 + j * 32 + w * 4 + grp;
    bias_[q] = b_mu[idx] + softplusf(b_rho[idx]) * eps_b[idx];
  }

  float cst0 = 0.f, cst1 = 0.f;

  // ---- publish h_0 = 0 into hbuf[0]
  if (w == 0) {
#pragma unroll
    for (int rg = 0; rg < 2; ++rg) {
      unsigned long long* dst = hbuf + (size_t)(0 * NG + g) * 4096 + (rg * 16 + j) * 128 + lane * 2;
      __hip_atomic_store(dst, 0ull, __ATOMIC_RELAXED, __HIP_MEMORY_SCOPE_AGENT);
      __hip_atomic_store(dst + 1, 0ull, __ATOMIC_RELAXED, __HIP_MEMORY_SCOPE_AGENT);
    }
    __builtin_amdgcn_fence(__ATOMIC_RELEASE, "agent");
    if (lane == 0)
      __hip_atomic_store(&flags[g * 16 + j], 1, __ATOMIC_RELAXED, __HIP_MEMORY_SCOPE_AGENT);
  }
  // ---- prefetch x_0 fragments into LDS (wave 1)
  if (w == 1) {
#pragma unroll
    for (int rg = 0; rg < 2; ++rg) {
      const float* xr = x + (size_t)(g * 32 + rg * 16 + srow) * (T_STEPS * D_IN);
#pragma unroll
      for (int kx = 0; kx < 3; ++kx) {
        int d0 = kx * 32 + grp * 8;
        unsigned short vs[8];
#pragma unroll
        for (int e = 0; e < 8; ++e) {
          int d = d0 + e;
          vs[e] = f2b(d < D_IN ? xr[d] : 0.f);
        }
        unsigned long long* dp = (unsigned long long*)&sm.s.x_lds[0][rg * 3 + kx][lane][0];
        dp[0] = pack4(vs);
        dp[1] = pack4(vs + 4);
      }
    }
  }
  __syncthreads();

  for (int t = 0; t < T_STEPS; ++t) {
    // ---- prefetch x_{t+1} (independent of flags) — wave 1
    if (w == 1 && (t + 1) < T_STEPS) {
      const int tn = t + 1;
#pragma unroll
      for (int rg = 0; rg < 2; ++rg) {
        const float* xr = x + (size_t)(g * 32 + rg * 16 + srow) * (T_STEPS * D_IN) + (size_t)tn * D_IN;
#pragma unroll
        for (int kx = 0; kx < 3; ++kx) {
          int d0 = kx * 32 + grp * 8;
          unsigned short vs[8];
#pragma unroll
          for (int e = 0; e < 8; ++e) {
            int d = d0 + e;
            vs[e] = f2b(d < D_IN ? xr[d] : 0.f);
          }
          unsigned long long* dp = (unsigned long long*)&sm.s.x_lds[tn & 1][rg * 3 + kx][lane][0];
          dp[0] = pack4(vs);
          dp[1] = pack4(vs + 4);
        }
      }
    }

    // ---- wait for all 16 producers of group g to publish h_t
    {
      const int tgt = t + 1;
      int ok;
      do {
        int f = __hip_atomic_load(&flags[g * 16 + srow], __ATOMIC_RELAXED, __HIP_MEMORY_SCOPE_AGENT);
        ok = (f >= tgt);
      } while (!__all(ok));
      __builtin_amdgcn_fence(__ATOMIC_ACQUIRE, "agent");
    }

    const unsigned long long* hb = hbuf + (size_t)((t & 1) * NG + g) * 4096;

    f32x4 acc0 = {0.f, 0.f, 0.f, 0.f}, acc1 = {0.f, 0.f, 0.f, 0.f};
    union FU { unsigned long long u[2]; short8 v; };
    FU fr[2][8];
#pragma unroll
    for (int kk = 0; kk < 8; ++kk) {
#pragma unroll
      for (int rg = 0; rg < 2; ++rg) {
        unsigned long long* p = (unsigned long long*)(hb + (rg * 16 + kk) * 128 + lane * 2);
        fr[rg][kk].u[0] = __hip_atomic_load(p, __ATOMIC_RELAXED, __HIP_MEMORY_SCOPE_AGENT);
        fr[rg][kk].u[1] = __hip_atomic_load(p + 1, __ATOMIC_RELAXED, __HIP_MEMORY_SCOPE_AGENT);
      }
    }
#pragma unroll
    for (int kk = 0; kk < 16; ++kk) {
      const int sl = kk & 7;
      short8 a0 = fr[0][sl].v;
      short8 a1 = fr[1][sl].v;
      if (kk < 8) {
        const int k2 = kk + 8;
#pragma unroll
        for (int rg = 0; rg < 2; ++rg) {
          unsigned long long* p = (unsigned long long*)(hb + (rg * 16 + k2) * 128 + lane * 2);
          fr[rg][sl].u[0] = __hip_atomic_load(p, __ATOMIC_RELAXED, __HIP_MEMORY_SCOPE_AGENT);
          fr[rg][sl].u[1] = __hip_atomic_load(p + 1, __ATOMIC_RELAXED, __HIP_MEMORY_SCOPE_AGENT);
        }
      }
      acc0 = __builtin_amdgcn_mfma_f32_16x16x32_bf16(a0, Wreg[kk], acc0, 0, 0, 0);
      acc1 = __builtin_amdgcn_mfma_f32_16x16x32_bf16(a1, Wreg[kk], acc1, 0, 0, 0);
    }
    // x contribution (K tiles 16..18)
#pragma unroll
    for (int kx = 0; kx < 3; ++kx) {
      short8 a0 = *(const short8*)&sm.s.x_lds[t & 1][0 * 3 + kx][lane][0];
      short8 a1 = *(const short8*)&sm.s.x_lds[t & 1][1 * 3 + kx][lane][0];
      acc0 = __builtin_amdgcn_mfma_f32_16x16x32_bf16(a0, Wreg[16 + kx], acc0, 0, 0, 0);
      acc1 = __builtin_amdgcn_mfma_f32_16x16x32_bf16(a1, Wreg[16 + kx], acc1, 0, 0, 0);
    }

    // ---- epilogue: transpose gates within wave, apply activations, update c,h
    {
      *(f32x4*)&sm.s.gatesT[w][0][srow][grp * 4] = acc0;
      *(f32x4*)&sm.s.gatesT[w][1][srow][grp * 4] = acc1;
#pragma unroll
      for (int rg = 0; rg < 2; ++rg) {
        float vi = sm.s.gatesT[w][rg][grp + 0][srow] + bias_[0];
        float vf = sm.s.gatesT[w][rg][grp + 4][srow] + bias_[1];
        float vg = sm.s.gatesT[w][rg][grp + 8][srow] + bias_[2];
        float vo = sm.s.gatesT[w][rg][grp + 12][srow] + bias_[3];
        float ii = sigmf(vi), ff = sigmf(vf);
        float gg = tanhf_(vg), oo = sigmf(vo);
        float cpr = rg ? cst1 : cst0;
        float cn = ff * cpr + ii * gg;
        if (rg) cst1 = cn; else cst0 = cn;
        float hh = oo * tanhf_(cn);
        sm.s.h_lds[t & 1][rg * 16 + srow][w * 4 + grp] = f2b(hh);
      }
    }
    __syncthreads();

    // ---- wave 0 assembles + publishes this block's h chunk (rows x 32 cols)
    if (w == 0) {
      unsigned long long* hbn = hbuf + (size_t)(((t + 1) & 1) * NG + g) * 4096;
#pragma unroll
      for (int rg = 0; rg < 2; ++rg) {
        const unsigned short* hp = &sm.s.h_lds[t & 1][rg * 16 + srow][grp * 8];
        unsigned long long u0 = ((const unsigned long long*)hp)[0];
        unsigned long long u1 = ((const unsigned long long*)hp)[1];
        unsigned long long* dst = hbn + (rg * 16 + j) * 128 + lane * 2;
        __hip_atomic_store(dst, u0, __ATOMIC_RELAXED, __HIP_MEMORY_SCOPE_AGENT);
        __hip_atomic_store(dst + 1, u1, __ATOMIC_RELAXED, __HIP_MEMORY_SCOPE_AGENT);
      }
      __builtin_amdgcn_fence(__ATOMIC_RELEASE, "agent");
      if (lane == 0)
        __hip_atomic_store(&flags[g * 16 + j], t + 2, __ATOMIC_RELAXED, __HIP_MEMORY_SCOPE_AGENT);
    }
  }

  // ---- final FC: z = h_T @ fc_w^T + fc_b  (j==0 blocks; h_512 is in hbuf[0])
  if (j == 0) {
    {
      int ok;
      do {
        int f = __hip_atomic_load(&flags[g * 16 + srow], __ATOMIC_RELAXED, __HIP_MEMORY_SCOPE_AGENT);
        ok = (f >= T_STEPS + 1);
      } while (!__all(ok));
      __builtin_amdgcn_fence(__ATOMIC_ACQUIRE, "agent");
    }
    __syncthreads();  // ensure in-loop smem uses are done before zbuf overwrite
    const unsigned long long* hb0 = hbuf + (size_t)(0 * NG + g) * 4096;
    for (int it = tid; it < 2048; it += 512) {
      unsigned long long* p = (unsigned long long*)(hb0 + it * 2);
      unsigned long long a = __hip_atomic_load(p, __ATOMIC_RELAXED, __HIP_MEMORY_SCOPE_AGENT);
      unsigned long long b = __hip_atomic_load(p + 1, __ATOMIC_RELAXED, __HIP_MEMORY_SCOPE_AGENT);
      ((unsigned long long*)sm.zbuf)[it * 2] = a;
      ((unsigned long long*)sm.zbuf)[it * 2 + 1] = b;
    }
    __syncthreads();
    for (int i = tid; i < 32 * NCLS_; i += 512) {
      int r = i / NCLS_, n = i % NCLS_;
      float s = fc_b[n];
      const float* fw = fc_w + n * H_DIM;
      int rg = r >> 4, rr = r & 15;
      for (int k = 0; k < H_DIM; ++k) {
        int kk = k >> 5, lch = rr + (((k >> 3) & 3) << 4), e = k & 7;
        unsigned short hu = ((const unsigned short*)sm.zbuf)[(((rg * 16 + kk) * 64 + lch) << 3) + e];
        s += b2f(hu) * fw[k];
      }
      out[(g * 32 + r) * NCLS_ + n] = s;
    }
  }
}

// ---------------------------------------------------------------------------
extern "C" void kernel_launch(void* const* d_in, const int* in_sizes, int n_in,
                              void* d_out, int out_size, void* d_ws, size_t ws_size,
                              hipStream_t stream) {
  const float* x       = (const float*)d_in[0];
  const float* wih_mu  = (const float*)d_in[1];
  const float* wih_rho = (const float*)d_in[2];
  const float* eps_ih  = (const float*)d_in[3];
  const float* whh_mu  = (const float*)d_in[4];
  const float* whh_rho = (const float*)d_in[5];
  const float* eps_hh  = (const float*)d_in[6];
  const float* b_mu    = (const float*)d_in[7];
  const float* b_rho   = (const float*)d_in[8];
  const float* eps_b   = (const float*)d_in[9];
  const float* fc_w    = (const float*)d_in[10];
  const float* fc_b    = (const float*)d_in[11];

  // ws layout: wpack [0, 2490368) | hbuf [2490368, 3014656) | flags [3014656, 3015168)
  unsigned short* wpack = (unsigned short*)d_ws;
  unsigned long long* hbuf = (unsigned long long*)((char*)d_ws + 2490368);
  int* flags = (int*)((char*)d_ws + 3014656);

  hipMemsetAsync(flags, 0, NG * NJ * sizeof(int), stream);
  pack_w_kernel<<<NJ * 8 * NKK, 64, 0, stream>>>(wih_mu, wih_rho, eps_ih,
                                                 whh_mu, whh_rho, eps_hh, wpack);
  lstm_scan_kernel<<<NG * NJ, 512, 0, stream>>>(x, wpack, b_mu, b_rho, eps_b,
                                                fc_w, fc_b, hbuf, flags,
                                                (float*)d_out);
}

// Round 2
// 5521.604 us; speedup vs baseline: 1.5294x; 1.5294x over previous
//
#include <hip/hip_runtime.h>
#include <hip/hip_bf16.h>

#define T_STEPS 512
#define D_IN 75
#define H_DIM 512
#define G_DIM 2048
#define NCLS_ 11
#define NKK 19           // 16 h-ktiles + 3 x-ktiles (K = 512 + 96pad = 608)
#define NG 8             // batch groups (32 rows each)
#define NJ 16            // column groups (32 h-cols each)

typedef __attribute__((ext_vector_type(8))) short short8;
typedef __attribute__((ext_vector_type(4))) float f32x4;

__device__ __forceinline__ unsigned short f2b(float f) {
  unsigned int u = __float_as_uint(f);
  unsigned int r = (u + 0x7fffu + ((u >> 16) & 1u)) >> 16;
  return (unsigned short)r;
}
__device__ __forceinline__ float b2f(unsigned short u) {
  return __uint_as_float(((unsigned int)u) << 16);
}
__device__ __forceinline__ float softplusf(float v) {
  return (v > 20.f) ? v : log1pf(__expf(v));
}
__device__ __forceinline__ float sigmf(float v) {
  return 1.f / (1.f + __expf(-v));
}
__device__ __forceinline__ float tanhf_(float v) {
  float a = fabsf(v);
  float e = __expf(-2.f * a);
  float r = (1.f - e) / (1.f + e);
  return copysignf(r, v);
}
__device__ __forceinline__ unsigned long long pack4(const unsigned short* v) {
  return (unsigned long long)v[0] | ((unsigned long long)v[1] << 16) |
         ((unsigned long long)v[2] << 32) | ((unsigned long long)v[3] << 48);
}

// ---------------------------------------------------------------------------
// Prologue: sample W = mu + softplus(rho)*eps for [w_hh; w_ih; 0pad] (608 x 2048)
// and pack into MFMA B-fragment chunks.
// Chunk c = (j*8 + wv)*19 + kk ; element (lane l, e):
//   k = kk*32 + (l>>4)*8 + e
//   n = 512*q + j*32 + wv*4 + cc   with  s=l&15, q=s>>2, cc=s&3
// ---------------------------------------------------------------------------
__global__ __launch_bounds__(64) void pack_w_kernel(
    const float* __restrict__ wih_mu, const float* __restrict__ wih_rho, const float* __restrict__ eps_ih,
    const float* __restrict__ whh_mu, const float* __restrict__ whh_rho, const float* __restrict__ eps_hh,
    unsigned short* __restrict__ wpack)
{
  int c = blockIdx.x;             // 0..2431
  int j = c / (8 * NKK);
  int r = c % (8 * NKK);
  int wv = r / NKK;
  int kk = r % NKK;
  int l = threadIdx.x;
  int s = l & 15, grp = l >> 4;
  int q = s >> 2, cc = s & 3;
  int n = q * 512 + j * 32 + wv * 4 + cc;
  unsigned short vs[8];
#pragma unroll
  for (int e = 0; e < 8; ++e) {
    int k = kk * 32 + grp * 8 + e;
    float val = 0.f;
    if (k < 512) {
      int idx = k * G_DIM + n;
      val = whh_mu[idx] + softplusf(whh_rho[idx]) * eps_hh[idx];
    } else if (k < 512 + D_IN) {
      int idx = (k - 512) * G_DIM + n;
      val = wih_mu[idx] + softplusf(wih_rho[idx]) * eps_ih[idx];
    }
    vs[e] = f2b(val);
  }
  unsigned long long u0 = pack4(vs);
  unsigned long long u1 = pack4(vs + 4);
  unsigned long long* dst = (unsigned long long*)wpack + (size_t)c * 128 + l * 2;
  dst[0] = u0;
  dst[1] = u1;
}

// ---------------------------------------------------------------------------
// Persistent scan kernel. 128 blocks = 8 batch-groups x 16 col-groups.
// Block (g,j): rows [g*32, +32), h-cols [j*32, +32). 4 waves x 8 cols each
// (2 mixed i/f/g/o tiles per wave; W slice = 2x19 short8 VGPRs, stationary).
// Per step: lane0-spin on group counter -> barrier -> stage h slice LLC->LDS
// (split across waves) -> barrier -> 76 MFMA from LDS A-frags -> gate
// epilogue -> barrier -> wave0 publishes h chunk (sc0sc1 atomics) ->
// s_waitcnt vmcnt(0) -> atomicAdd group counter. NO agent fences (no
// buffer_inv/wbl2): all cross-block data is L2-bypassing atomics, so x/W
// stay L2-cached.
// ---------------------------------------------------------------------------
struct SmemLoop {
  unsigned short hstage[32][64][8];   // 32KB  staged h chunks, A-frag layout
  float gatesT[4][2][2][16][20];      // 20KB  [wave][ct][rg][slotN][rowM pad20]
  unsigned short h_lds[32][36];       // 2.25KB padded rows (72B)
  unsigned short x_lds[2][6][64][8];  // 12KB  [buf][rg*3+kx][lane][e]
};
union Smem {
  SmemLoop s;
  unsigned short zbuf[32][512];       // 32KB (post-loop only)
};

__global__ __launch_bounds__(256, 1) void lstm_scan_kernel(
    const float* __restrict__ x,
    const unsigned short* __restrict__ wpack,
    const float* __restrict__ b_mu, const float* __restrict__ b_rho, const float* __restrict__ eps_b,
    const float* __restrict__ fc_w, const float* __restrict__ fc_b,
    unsigned long long* __restrict__ hbuf, int* __restrict__ ctr,
    float* __restrict__ out)
{
  __shared__ Smem sm;

  const int bid = blockIdx.x;
  const int g = bid >> 4, j = bid & 15;
  const int tid = threadIdx.x;
  const int w = tid >> 6, lane = tid & 63;
  const int srow = lane & 15, grp = lane >> 4;
  int* myctr = &ctr[g];

  // ---- load stationary W fragments (2 col-tiles x 19 ktiles x 16B per lane)
  short8 Wreg[2][NKK];
  {
    const short8* wp = (const short8*)wpack;
#pragma unroll
    for (int ct = 0; ct < 2; ++ct) {
      const int cj = (j * 8 + w * 2 + ct) * NKK;
#pragma unroll
      for (int kk = 0; kk < NKK; ++kk)
        Wreg[ct][kk] = wp[(size_t)(cj + kk) * 64 + lane];
    }
  }
  // ---- sampled bias (epilogue lane role: row=srow, cc=grp)
  float bias_[2][4];
#pragma unroll
  for (int ct = 0; ct < 2; ++ct)
#pragma unroll
    for (int q = 0; q < 4; ++q) {
      int idx = q * 512 + j * 32 + (w * 2 + ct) * 4 + grp;
      bias_[ct][q] = b_mu[idx] + softplusf(b_rho[idx]) * eps_b[idx];
    }

  float cst[2][2] = {{0.f, 0.f}, {0.f, 0.f}};

  // ---- publish h_0 = 0 into hbuf[0]
  if (w == 0) {
#pragma unroll
    for (int rg = 0; rg < 2; ++rg) {
      unsigned long long* dst = hbuf + (size_t)(0 * NG + g) * 4096 + (rg * 16 + j) * 128 + lane * 2;
      __hip_atomic_store(dst, 0ull, __ATOMIC_RELAXED, __HIP_MEMORY_SCOPE_AGENT);
      __hip_atomic_store(dst + 1, 0ull, __ATOMIC_RELAXED, __HIP_MEMORY_SCOPE_AGENT);
    }
    asm volatile("s_waitcnt vmcnt(0)" ::: "memory");
    if (lane == 0)
      __hip_atomic_fetch_add(myctr, 1, __ATOMIC_RELAXED, __HIP_MEMORY_SCOPE_AGENT);
  }
  // ---- prefetch x_0 fragments into LDS (wave 1)
  if (w == 1) {
#pragma unroll
    for (int rg = 0; rg < 2; ++rg) {
      const float* xr = x + (size_t)(g * 32 + rg * 16 + srow) * (T_STEPS * D_IN);
#pragma unroll
      for (int kx = 0; kx < 3; ++kx) {
        int d0 = kx * 32 + grp * 8;
        unsigned short vs[8];
#pragma unroll
        for (int e = 0; e < 8; ++e) {
          int d = d0 + e;
          vs[e] = f2b(d < D_IN ? xr[d] : 0.f);
        }
        unsigned long long* dp = (unsigned long long*)&sm.s.x_lds[0][rg * 3 + kx][lane][0];
        dp[0] = pack4(vs);
        dp[1] = pack4(vs + 4);
      }
    }
  }

  for (int t = 0; t < T_STEPS; ++t) {
    // ---- prefetch x_{t+1} (independent of sync) — wave 1
    if (w == 1 && (t + 1) < T_STEPS) {
      const int tn = t + 1;
#pragma unroll
      for (int rg = 0; rg < 2; ++rg) {
        const float* xr = x + (size_t)(g * 32 + rg * 16 + srow) * (T_STEPS * D_IN) + (size_t)tn * D_IN;
#pragma unroll
        for (int kx = 0; kx < 3; ++kx) {
          int d0 = kx * 32 + grp * 8;
          unsigned short vs[8];
#pragma unroll
          for (int e = 0; e < 8; ++e) {
            int d = d0 + e;
            vs[e] = f2b(d < D_IN ? xr[d] : 0.f);
          }
          unsigned long long* dp = (unsigned long long*)&sm.s.x_lds[tn & 1][rg * 3 + kx][lane][0];
          dp[0] = pack4(vs);
          dp[1] = pack4(vs + 4);
        }
      }
    }

    // ---- single-lane spin for all 16 producers of group g
    if (w == 0 && lane == 0) {
      const int tgt = 16 * (t + 1);
      while (__hip_atomic_load(myctr, __ATOMIC_RELAXED, __HIP_MEMORY_SCOPE_AGENT) < tgt)
        __builtin_amdgcn_s_sleep(1);
    }
    __syncthreads();   // A: h_t visible at LLC

    // ---- stage h slice LLC -> LDS (8 chunks of 1KB per wave)
    const unsigned long long* hb = hbuf + (size_t)((t & 1) * NG + g) * 4096;
#pragma unroll
    for (int c8 = 0; c8 < 8; ++c8) {
      const int chunk = w * 8 + c8;
      const unsigned long long* p = hb + chunk * 128 + lane * 2;
      unsigned long long u0 = __hip_atomic_load(p, __ATOMIC_RELAXED, __HIP_MEMORY_SCOPE_AGENT);
      unsigned long long u1 = __hip_atomic_load(p + 1, __ATOMIC_RELAXED, __HIP_MEMORY_SCOPE_AGENT);
      unsigned long long* dp = (unsigned long long*)&sm.s.hstage[chunk][lane][0];
      dp[0] = u0;
      dp[1] = u1;
    }
    __syncthreads();   // B: hstage complete

    f32x4 acc[2][2];
#pragma unroll
    for (int ct = 0; ct < 2; ++ct)
#pragma unroll
      for (int rg = 0; rg < 2; ++rg)
        acc[ct][rg] = (f32x4){0.f, 0.f, 0.f, 0.f};

#pragma unroll
    for (int kk = 0; kk < 16; ++kk) {
      short8 a0 = *(const short8*)&sm.s.hstage[kk][lane][0];       // rg0
      short8 a1 = *(const short8*)&sm.s.hstage[16 + kk][lane][0];  // rg1
      acc[0][0] = __builtin_amdgcn_mfma_f32_16x16x32_bf16(a0, Wreg[0][kk], acc[0][0], 0, 0, 0);
      acc[1][0] = __builtin_amdgcn_mfma_f32_16x16x32_bf16(a0, Wreg[1][kk], acc[1][0], 0, 0, 0);
      acc[0][1] = __builtin_amdgcn_mfma_f32_16x16x32_bf16(a1, Wreg[0][kk], acc[0][1], 0, 0, 0);
      acc[1][1] = __builtin_amdgcn_mfma_f32_16x16x32_bf16(a1, Wreg[1][kk], acc[1][1], 0, 0, 0);
    }
#pragma unroll
    for (int kx = 0; kx < 3; ++kx) {
      short8 a0 = *(const short8*)&sm.s.x_lds[t & 1][kx][lane][0];      // rg0
      short8 a1 = *(const short8*)&sm.s.x_lds[t & 1][3 + kx][lane][0];  // rg1
      acc[0][0] = __builtin_amdgcn_mfma_f32_16x16x32_bf16(a0, Wreg[0][16 + kx], acc[0][0], 0, 0, 0);
      acc[1][0] = __builtin_amdgcn_mfma_f32_16x16x32_bf16(a0, Wreg[1][16 + kx], acc[1][0], 0, 0, 0);
      acc[0][1] = __builtin_amdgcn_mfma_f32_16x16x32_bf16(a1, Wreg[0][16 + kx], acc[0][1], 0, 0, 0);
      acc[1][1] = __builtin_amdgcn_mfma_f32_16x16x32_bf16(a1, Wreg[1][16 + kx], acc[1][1], 0, 0, 0);
    }

    // ---- epilogue: transpose gates within wave, activations, update c,h
#pragma unroll
    for (int ct = 0; ct < 2; ++ct) {
      *(f32x4*)&sm.s.gatesT[w][ct][0][srow][grp * 4] = acc[ct][0];
      *(f32x4*)&sm.s.gatesT[w][ct][1][srow][grp * 4] = acc[ct][1];
    }
#pragma unroll
    for (int ct = 0; ct < 2; ++ct)
#pragma unroll
      for (int rg = 0; rg < 2; ++rg) {
        float vi = sm.s.gatesT[w][ct][rg][grp + 0][srow] + bias_[ct][0];
        float vf = sm.s.gatesT[w][ct][rg][grp + 4][srow] + bias_[ct][1];
        float vg = sm.s.gatesT[w][ct][rg][grp + 8][srow] + bias_[ct][2];
        float vo = sm.s.gatesT[w][ct][rg][grp + 12][srow] + bias_[ct][3];
        float ii = sigmf(vi), ff = sigmf(vf);
        float gg = tanhf_(vg), oo = sigmf(vo);
        float cn = ff * cst[ct][rg] + ii * gg;
        cst[ct][rg] = cn;
        float hh = oo * tanhf_(cn);
        sm.s.h_lds[rg * 16 + srow][(w * 2 + ct) * 4 + grp] = f2b(hh);
      }
    __syncthreads();   // C: h_lds complete

    // ---- wave 0 publishes this block's h chunk + bumps group counter
    if (w == 0) {
      unsigned long long* hbn = hbuf + (size_t)(((t + 1) & 1) * NG + g) * 4096;
#pragma unroll
      for (int rg = 0; rg < 2; ++rg) {
        const unsigned short* hp = &sm.s.h_lds[rg * 16 + srow][grp * 8];
        unsigned long long u0 = ((const unsigned long long*)hp)[0];
        unsigned long long u1 = ((const unsigned long long*)hp)[1];
        unsigned long long* dst = hbn + (rg * 16 + j) * 128 + lane * 2;
        __hip_atomic_store(dst, u0, __ATOMIC_RELAXED, __HIP_MEMORY_SCOPE_AGENT);
        __hip_atomic_store(dst + 1, u1, __ATOMIC_RELAXED, __HIP_MEMORY_SCOPE_AGENT);
      }
      asm volatile("s_waitcnt vmcnt(0)" ::: "memory");
      if (lane == 0)
        __hip_atomic_fetch_add(myctr, 1, __ATOMIC_RELAXED, __HIP_MEMORY_SCOPE_AGENT);
    }
  }

  // ---- final FC: z = h_T @ fc_w^T + fc_b  (j==0 blocks; h_512 is in hbuf[0])
  if (j == 0) {
    if (w == 0 && lane == 0) {
      const int tgt = 16 * (T_STEPS + 1);
      while (__hip_atomic_load(myctr, __ATOMIC_RELAXED, __HIP_MEMORY_SCOPE_AGENT) < tgt)
        __builtin_amdgcn_s_sleep(1);
    }
    __syncthreads();   // releases block; also orders wave0's publish before zbuf overwrite
    const unsigned long long* hb0 = hbuf + (size_t)(0 * NG + g) * 4096;
    for (int it = tid; it < 2048; it += 256) {
      const unsigned long long* p = hb0 + it * 2;
      unsigned long long a = __hip_atomic_load(p, __ATOMIC_RELAXED, __HIP_MEMORY_SCOPE_AGENT);
      unsigned long long b = __hip_atomic_load(p + 1, __ATOMIC_RELAXED, __HIP_MEMORY_SCOPE_AGENT);
      ((unsigned long long*)sm.zbuf)[it * 2] = a;
      ((unsigned long long*)sm.zbuf)[it * 2 + 1] = b;
    }
    __syncthreads();
    for (int i = tid; i < 32 * NCLS_; i += 256) {
      int r = i / NCLS_, n = i % NCLS_;
      float s = fc_b[n];
      const float* fw = fc_w + n * H_DIM;
      int rg = r >> 4, rr = r & 15;
      for (int k = 0; k < H_DIM; ++k) {
        int kk = k >> 5, lch = rr + (((k >> 3) & 3) << 4), e = k & 7;
        unsigned short hu = ((const unsigned short*)sm.zbuf)[(((rg * 16 + kk) * 64 + lch) << 3) + e];
        s += b2f(hu) * fw[k];
      }
      out[(g * 32 + r) * NCLS_ + n] = s;
    }
  }
}

// ---------------------------------------------------------------------------
extern "C" void kernel_launch(void* const* d_in, const int* in_sizes, int n_in,
                              void* d_out, int out_size, void* d_ws, size_t ws_size,
                              hipStream_t stream) {
  const float* x       = (const float*)d_in[0];
  const float* wih_mu  = (const float*)d_in[1];
  const float* wih_rho = (const float*)d_in[2];
  const float* eps_ih  = (const float*)d_in[3];
  const float* whh_mu  = (const float*)d_in[4];
  const float* whh_rho = (const float*)d_in[5];
  const float* eps_hh  = (const float*)d_in[6];
  const float* b_mu    = (const float*)d_in[7];
  const float* b_rho   = (const float*)d_in[8];
  const float* eps_b   = (const float*)d_in[9];
  const float* fc_w    = (const float*)d_in[10];
  const float* fc_b    = (const float*)d_in[11];

  // ws layout: wpack [0, 2490368) | hbuf [2490368, 3014656) | ctr [3014656, +32)
  unsigned short* wpack = (unsigned short*)d_ws;
  unsigned long long* hbuf = (unsigned long long*)((char*)d_ws + 2490368);
  int* ctr = (int*)((char*)d_ws + 3014656);

  hipMemsetAsync(ctr, 0, NG * sizeof(int), stream);
  pack_w_kernel<<<NJ * 8 * NKK, 64, 0, stream>>>(wih_mu, wih_rho, eps_ih,
                                                 whh_mu, whh_rho, eps_hh, wpack);
  lstm_scan_kernel<<<NG * NJ, 256, 0, stream>>>(x, wpack, b_mu, b_rho, eps_b,
                                                fc_w, fc_b, hbuf, ctr,
                                                (float*)d_out);
}

// Round 3
// 3946.307 us; speedup vs baseline: 2.1399x; 1.3992x over previous
//
#include <hip/hip_runtime.h>
#include <hip/hip_bf16.h>

#define T_STEPS 512
#define D_IN 75
#define H_DIM 512
#define G_DIM 2048
#define NCLS_ 11
#define NKK 19           // 16 h-ktiles + 3 x-ktiles (K = 512 + 96pad = 608)
#define NG 8             // batch groups (32 rows each)
#define NJ 16            // column groups (32 h-cols each)

typedef __attribute__((ext_vector_type(8))) short short8;
typedef __attribute__((ext_vector_type(4))) float f32x4;

__device__ __forceinline__ unsigned short f2b(float f) {
  unsigned int u = __float_as_uint(f);
  unsigned int r = (u + 0x7fffu + ((u >> 16) & 1u)) >> 16;
  return (unsigned short)r;
}
__device__ __forceinline__ float b2f(unsigned short u) {
  return __uint_as_float(((unsigned int)u) << 16);
}
__device__ __forceinline__ float softplusf(float v) {
  return (v > 20.f) ? v : log1pf(__expf(v));
}
__device__ __forceinline__ float sigmf(float v) {
  return 1.f / (1.f + __expf(-v));
}
__device__ __forceinline__ float tanhf_(float v) {
  float a = fabsf(v);
  float e = __expf(-2.f * a);
  float r = (1.f - e) / (1.f + e);
  return copysignf(r, v);
}
__device__ __forceinline__ unsigned long long pack4(const unsigned short* v) {
  return (unsigned long long)v[0] | ((unsigned long long)v[1] << 16) |
         ((unsigned long long)v[2] << 32) | ((unsigned long long)v[3] << 48);
}

// ---------------------------------------------------------------------------
// Prologue: sample W = mu + softplus(rho)*eps for [w_hh; w_ih; 0pad] (608 x 2048)
// and pack into MFMA B-fragment chunks.
// ---------------------------------------------------------------------------
__global__ __launch_bounds__(64) void pack_w_kernel(
    const float* __restrict__ wih_mu, const float* __restrict__ wih_rho, const float* __restrict__ eps_ih,
    const float* __restrict__ whh_mu, const float* __restrict__ whh_rho, const float* __restrict__ eps_hh,
    unsigned short* __restrict__ wpack)
{
  int c = blockIdx.x;             // 0..2431
  int j = c / (8 * NKK);
  int r = c % (8 * NKK);
  int wv = r / NKK;
  int kk = r % NKK;
  int l = threadIdx.x;
  int s = l & 15, grp = l >> 4;
  int q = s >> 2, cc = s & 3;
  int n = q * 512 + j * 32 + wv * 4 + cc;
  unsigned short vs[8];
#pragma unroll
  for (int e = 0; e < 8; ++e) {
    int k = kk * 32 + grp * 8 + e;
    float val = 0.f;
    if (k < 512) {
      int idx = k * G_DIM + n;
      val = whh_mu[idx] + softplusf(whh_rho[idx]) * eps_hh[idx];
    } else if (k < 512 + D_IN) {
      int idx = (k - 512) * G_DIM + n;
      val = wih_mu[idx] + softplusf(wih_rho[idx]) * eps_ih[idx];
    }
    vs[e] = f2b(val);
  }
  unsigned long long u0 = pack4(vs);
  unsigned long long u1 = pack4(vs + 4);
  unsigned long long* dst = (unsigned long long*)wpack + (size_t)c * 128 + l * 2;
  dst[0] = u0;
  dst[1] = u1;
}

// ---------------------------------------------------------------------------
// Persistent scan kernel. 128 blocks; g = bid&7 (XCD-clustered: all 16 blocks
// of a group land on one XCD via the bid%8 round-robin), j = bid>>3.
// Block (g,j): rows [g*32,+32), h-cols [j*32,+32). 4 waves x 8 cols.
// Sync: per-block flags on private 64B lines, store-release (vmcnt(0)) only,
// no RMW. All 4 waves poll (16 lanes, strided flags), then stage their own
// 8 chunks LLC->LDS. Wave1 issues x_{t+1} loads into regs BEFORE polling and
// commits them to LDS AFTER the MFMA phase (HBM latency hidden).
// ---------------------------------------------------------------------------
struct SmemLoop {
  unsigned short hstage[32][64][8];   // 32KB  staged h chunks, A-frag layout
  float gatesT[4][2][2][16][20];      // 20KB  [wave][ct][rg][slotN][rowM pad20]
  unsigned short h_lds[32][36];       // 2.25KB padded rows (72B)
  unsigned short x_lds[2][6][64][8];  // 12KB  [buf][rg*3+kx][lane][e]
};
union Smem {
  SmemLoop s;
  unsigned short zbuf[32][512];       // 32KB (post-loop only)
};

__global__ __launch_bounds__(256, 1) void lstm_scan_kernel(
    const float* __restrict__ x,
    const unsigned short* __restrict__ wpack,
    const float* __restrict__ b_mu, const float* __restrict__ b_rho, const float* __restrict__ eps_b,
    const float* __restrict__ fc_w, const float* __restrict__ fc_b,
    unsigned long long* __restrict__ hbuf, int* __restrict__ flags,
    float* __restrict__ out)
{
  __shared__ Smem sm;

  const int bid = blockIdx.x;
  const int g = bid & 7, j = bid >> 3;      // XCD-clustered groups
  const int tid = threadIdx.x;
  const int w = tid >> 6, lane = tid & 63;
  const int srow = lane & 15, grp = lane >> 4;

  // ---- load stationary W fragments (2 col-tiles x 19 ktiles x 16B per lane)
  short8 Wreg[2][NKK];
  {
    const short8* wp = (const short8*)wpack;
#pragma unroll
    for (int ct = 0; ct < 2; ++ct) {
      const int cj = (j * 8 + w * 2 + ct) * NKK;
#pragma unroll
      for (int kk = 0; kk < NKK; ++kk)
        Wreg[ct][kk] = wp[(size_t)(cj + kk) * 64 + lane];
    }
  }
  // ---- sampled bias (epilogue lane role: row=srow, cc=grp)
  float bias_[2][4];
#pragma unroll
  for (int ct = 0; ct < 2; ++ct)
#pragma unroll
    for (int q = 0; q < 4; ++q) {
      int idx = q * 512 + j * 32 + (w * 2 + ct) * 4 + grp;
      bias_[ct][q] = b_mu[idx] + softplusf(b_rho[idx]) * eps_b[idx];
    }

  float cst[2][2] = {{0.f, 0.f}, {0.f, 0.f}};

  // ---- publish h_0 = 0 into hbuf[0]
  if (w == 0) {
#pragma unroll
    for (int rg = 0; rg < 2; ++rg) {
      unsigned long long* dst = hbuf + (size_t)(0 * NG + g) * 4096 + (rg * 16 + j) * 128 + lane * 2;
      __hip_atomic_store(dst, 0ull, __ATOMIC_RELAXED, __HIP_MEMORY_SCOPE_AGENT);
      __hip_atomic_store(dst + 1, 0ull, __ATOMIC_RELAXED, __HIP_MEMORY_SCOPE_AGENT);
    }
    asm volatile("s_waitcnt vmcnt(0)" ::: "memory");
    if (lane == 0)
      __hip_atomic_store(&flags[(g * 16 + j) * 16], 1, __ATOMIC_RELAXED, __HIP_MEMORY_SCOPE_AGENT);
  }
  // ---- x_0 fragments into LDS (wave 1)
  if (w == 1) {
#pragma unroll
    for (int rg = 0; rg < 2; ++rg) {
      const float* xr = x + (size_t)(g * 32 + rg * 16 + srow) * (T_STEPS * D_IN);
#pragma unroll
      for (int kx = 0; kx < 3; ++kx) {
        int d0 = kx * 32 + grp * 8;
        unsigned short vs[8];
#pragma unroll
        for (int e = 0; e < 8; ++e) {
          int d = d0 + e;
          vs[e] = f2b(d < D_IN ? xr[d] : 0.f);
        }
        unsigned long long* dp = (unsigned long long*)&sm.s.x_lds[0][rg * 3 + kx][lane][0];
        dp[0] = pack4(vs);
        dp[1] = pack4(vs + 4);
      }
    }
  }

  for (int t = 0; t < T_STEPS; ++t) {
    // ---- wave1: ISSUE x_{t+1} loads into registers (latency hidden under
    //      spin + stage + MFMA; committed to LDS after the MFMA phase)
    float xv[2][3][8];
    const bool xpre = (w == 1) && (t + 1 < T_STEPS);
    if (xpre) {
      const int tn = t + 1;
#pragma unroll
      for (int rg = 0; rg < 2; ++rg) {
        const float* xr = x + (size_t)(g * 32 + rg * 16 + srow) * (T_STEPS * D_IN) + (size_t)tn * D_IN;
#pragma unroll
        for (int kx = 0; kx < 3; ++kx) {
          int d0 = kx * 32 + grp * 8;
#pragma unroll
          for (int e = 0; e < 8; ++e) {
            int d = d0 + e;
            xv[rg][kx][e] = (d < D_IN) ? xr[d] : 0.f;
          }
        }
      }
    }

    // ---- poll all 16 producer flags of group g (all waves; 64B-strided lines)
    {
      const int tgt = t + 1;
      int* fp = &flags[(g * 16 + (lane & 15)) * 16];
      while (true) {
        int f = (lane < 16)
                    ? __hip_atomic_load(fp, __ATOMIC_RELAXED, __HIP_MEMORY_SCOPE_AGENT)
                    : 0x7fffffff;
        if (__all(f >= tgt)) break;
        __builtin_amdgcn_s_sleep(1);
      }
    }

    // ---- stage h slice LLC -> LDS (8 chunks of 1KB per wave)
    const unsigned long long* hb = hbuf + (size_t)((t & 1) * NG + g) * 4096;
#pragma unroll
    for (int c8 = 0; c8 < 8; ++c8) {
      const int chunk = w * 8 + c8;
      const unsigned long long* p = hb + chunk * 128 + lane * 2;
      unsigned long long u0 = __hip_atomic_load(p, __ATOMIC_RELAXED, __HIP_MEMORY_SCOPE_AGENT);
      unsigned long long u1 = __hip_atomic_load(p + 1, __ATOMIC_RELAXED, __HIP_MEMORY_SCOPE_AGENT);
      unsigned long long* dp = (unsigned long long*)&sm.s.hstage[chunk][lane][0];
      dp[0] = u0;
      dp[1] = u1;
    }
    __syncthreads();   // B: hstage complete

    f32x4 acc[2][2];
#pragma unroll
    for (int ct = 0; ct < 2; ++ct)
#pragma unroll
      for (int rg = 0; rg < 2; ++rg)
        acc[ct][rg] = (f32x4){0.f, 0.f, 0.f, 0.f};

#pragma unroll
    for (int kk = 0; kk < 16; ++kk) {
      short8 a0 = *(const short8*)&sm.s.hstage[kk][lane][0];       // rg0
      short8 a1 = *(const short8*)&sm.s.hstage[16 + kk][lane][0];  // rg1
      acc[0][0] = __builtin_amdgcn_mfma_f32_16x16x32_bf16(a0, Wreg[0][kk], acc[0][0], 0, 0, 0);
      acc[1][0] = __builtin_amdgcn_mfma_f32_16x16x32_bf16(a0, Wreg[1][kk], acc[1][0], 0, 0, 0);
      acc[0][1] = __builtin_amdgcn_mfma_f32_16x16x32_bf16(a1, Wreg[0][kk], acc[0][1], 0, 0, 0);
      acc[1][1] = __builtin_amdgcn_mfma_f32_16x16x32_bf16(a1, Wreg[1][kk], acc[1][1], 0, 0, 0);
    }
#pragma unroll
    for (int kx = 0; kx < 3; ++kx) {
      short8 a0 = *(const short8*)&sm.s.x_lds[t & 1][kx][lane][0];      // rg0
      short8 a1 = *(const short8*)&sm.s.x_lds[t & 1][3 + kx][lane][0];  // rg1
      acc[0][0] = __builtin_amdgcn_mfma_f32_16x16x32_bf16(a0, Wreg[0][16 + kx], acc[0][0], 0, 0, 0);
      acc[1][0] = __builtin_amdgcn_mfma_f32_16x16x32_bf16(a0, Wreg[1][16 + kx], acc[1][0], 0, 0, 0);
      acc[0][1] = __builtin_amdgcn_mfma_f32_16x16x32_bf16(a1, Wreg[0][16 + kx], acc[0][1], 0, 0, 0);
      acc[1][1] = __builtin_amdgcn_mfma_f32_16x16x32_bf16(a1, Wreg[1][16 + kx], acc[1][1], 0, 0, 0);
    }

    // ---- wave1: commit x_{t+1} registers to LDS (loads have had ~whole
    //      spin+stage+MFMA window to land)
    if (xpre) {
      const int tn = t + 1;
#pragma unroll
      for (int rg = 0; rg < 2; ++rg)
#pragma unroll
        for (int kx = 0; kx < 3; ++kx) {
          unsigned short vs[8];
#pragma unroll
          for (int e = 0; e < 8; ++e) vs[e] = f2b(xv[rg][kx][e]);
          unsigned long long* dp = (unsigned long long*)&sm.s.x_lds[tn & 1][rg * 3 + kx][lane][0];
          dp[0] = pack4(vs);
          dp[1] = pack4(vs + 4);
        }
    }

    // ---- epilogue: transpose gates within wave, activations, update c,h
#pragma unroll
    for (int ct = 0; ct < 2; ++ct) {
      *(f32x4*)&sm.s.gatesT[w][ct][0][srow][grp * 4] = acc[ct][0];
      *(f32x4*)&sm.s.gatesT[w][ct][1][srow][grp * 4] = acc[ct][1];
    }
#pragma unroll
    for (int ct = 0; ct < 2; ++ct)
#pragma unroll
      for (int rg = 0; rg < 2; ++rg) {
        float vi = sm.s.gatesT[w][ct][rg][grp + 0][srow] + bias_[ct][0];
        float vf = sm.s.gatesT[w][ct][rg][grp + 4][srow] + bias_[ct][1];
        float vg = sm.s.gatesT[w][ct][rg][grp + 8][srow] + bias_[ct][2];
        float vo = sm.s.gatesT[w][ct][rg][grp + 12][srow] + bias_[ct][3];
        float ii = sigmf(vi), ff = sigmf(vf);
        float gg = tanhf_(vg), oo = sigmf(vo);
        float cn = ff * cst[ct][rg] + ii * gg;
        cst[ct][rg] = cn;
        float hh = oo * tanhf_(cn);
        sm.s.h_lds[rg * 16 + srow][(w * 2 + ct) * 4 + grp] = f2b(hh);
      }
    __syncthreads();   // C: h_lds complete (also fences hstage/x_lds reuse)

    // ---- wave 0 publishes this block's h chunk + releases its flag
    if (w == 0) {
      unsigned long long* hbn = hbuf + (size_t)(((t + 1) & 1) * NG + g) * 4096;
#pragma unroll
      for (int rg = 0; rg < 2; ++rg) {
        const unsigned short* hp = &sm.s.h_lds[rg * 16 + srow][grp * 8];
        unsigned long long u0 = ((const unsigned long long*)hp)[0];
        unsigned long long u1 = ((const unsigned long long*)hp)[1];
        unsigned long long* dst = hbn + (rg * 16 + j) * 128 + lane * 2;
        __hip_atomic_store(dst, u0, __ATOMIC_RELAXED, __HIP_MEMORY_SCOPE_AGENT);
        __hip_atomic_store(dst + 1, u1, __ATOMIC_RELAXED, __HIP_MEMORY_SCOPE_AGENT);
      }
      asm volatile("s_waitcnt vmcnt(0)" ::: "memory");
      if (lane == 0)
        __hip_atomic_store(&flags[(g * 16 + j) * 16], t + 2, __ATOMIC_RELAXED, __HIP_MEMORY_SCOPE_AGENT);
    }
  }

  // ---- final FC: z = h_T @ fc_w^T + fc_b  (j==0 blocks; h_512 is in hbuf[0])
  if (j == 0) {
    if (w == 0) {
      const int tgt = T_STEPS + 1;
      int* fp = &flags[(g * 16 + (lane & 15)) * 16];
      while (true) {
        int f = (lane < 16)
                    ? __hip_atomic_load(fp, __ATOMIC_RELAXED, __HIP_MEMORY_SCOPE_AGENT)
                    : 0x7fffffff;
        if (__all(f >= tgt)) break;
        __builtin_amdgcn_s_sleep(1);
      }
    }
    __syncthreads();   // releases block; orders in-loop smem uses before zbuf overwrite
    const unsigned long long* hb0 = hbuf + (size_t)(0 * NG + g) * 4096;
    for (int it = tid; it < 2048; it += 256) {
      const unsigned long long* p = hb0 + it * 2;
      unsigned long long a = __hip_atomic_load(p, __ATOMIC_RELAXED, __HIP_MEMORY_SCOPE_AGENT);
      unsigned long long b = __hip_atomic_load(p + 1, __ATOMIC_RELAXED, __HIP_MEMORY_SCOPE_AGENT);
      ((unsigned long long*)sm.zbuf)[it * 2] = a;
      ((unsigned long long*)sm.zbuf)[it * 2 + 1] = b;
    }
    __syncthreads();
    for (int i = tid; i < 32 * NCLS_; i += 256) {
      int r = i / NCLS_, n = i % NCLS_;
      float s = fc_b[n];
      const float* fw = fc_w + n * H_DIM;
      int rg = r >> 4, rr = r & 15;
      for (int k = 0; k < H_DIM; ++k) {
        int kk = k >> 5, lch = rr + (((k >> 3) & 3) << 4), e = k & 7;
        unsigned short hu = ((const unsigned short*)sm.zbuf)[(((rg * 16 + kk) * 64 + lch) << 3) + e];
        s += b2f(hu) * fw[k];
      }
      out[(g * 32 + r) * NCLS_ + n] = s;
    }
  }
}

// ---------------------------------------------------------------------------
extern "C" void kernel_launch(void* const* d_in, const int* in_sizes, int n_in,
                              void* d_out, int out_size, void* d_ws, size_t ws_size,
                              hipStream_t stream) {
  const float* x       = (const float*)d_in[0];
  const float* wih_mu  = (const float*)d_in[1];
  const float* wih_rho = (const float*)d_in[2];
  const float* eps_ih  = (const float*)d_in[3];
  const float* whh_mu  = (const float*)d_in[4];
  const float* whh_rho = (const float*)d_in[5];
  const float* eps_hh  = (const float*)d_in[6];
  const float* b_mu    = (const float*)d_in[7];
  const float* b_rho   = (const float*)d_in[8];
  const float* eps_b   = (const float*)d_in[9];
  const float* fc_w    = (const float*)d_in[10];
  const float* fc_b    = (const float*)d_in[11];

  // ws layout: wpack [0, 2490368) | hbuf [2490368, 3014656) | flags [3014656, +8192)
  unsigned short* wpack = (unsigned short*)d_ws;
  unsigned long long* hbuf = (unsigned long long*)((char*)d_ws + 2490368);
  int* flags = (int*)((char*)d_ws + 3014656);

  hipMemsetAsync(flags, 0, NG * NJ * 16 * sizeof(int), stream);
  pack_w_kernel<<<NJ * 8 * NKK, 64, 0, stream>>>(wih_mu, wih_rho, eps_ih,
                                                 whh_mu, whh_rho, eps_hh, wpack);
  lstm_scan_kernel<<<NG * NJ, 256, 0, stream>>>(x, wpack, b_mu, b_rho, eps_b,
                                                fc_w, fc_b, hbuf, flags,
                                                (float*)d_out);
}

// Round 6
// 3068.896 us; speedup vs baseline: 2.7517x; 1.2859x over previous
//
#include <hip/hip_runtime.h>
#include <hip/hip_bf16.h>

#define T_STEPS 512
#define D_IN 75
#define H_DIM 512
#define G_DIM 2048
#define NCLS_ 11
#define NKK 19           // 16 h-ktiles + 3 x-ktiles (K = 512 + 96pad = 608)
#define NG 8             // batch groups (32 rows each)
#define NJ 16            // column groups (32 h-cols each)

typedef __attribute__((ext_vector_type(8))) short short8;
typedef __attribute__((ext_vector_type(4))) float f32x4;

__device__ __forceinline__ unsigned short f2b(float f) {
  unsigned int u = __float_as_uint(f);
  unsigned int r = (u + 0x7fffu + ((u >> 16) & 1u)) >> 16;
  return (unsigned short)r;
}
__device__ __forceinline__ float b2f(unsigned short u) {
  return __uint_as_float(((unsigned int)u) << 16);
}
__device__ __forceinline__ float softplusf(float v) {
  return (v > 20.f) ? v : log1pf(__expf(v));
}
__device__ __forceinline__ float sigmf(float v) {
  return 1.f / (1.f + __expf(-v));
}
__device__ __forceinline__ float tanhf_(float v) {
  float a = fabsf(v);
  float e = __expf(-2.f * a);
  float r = (1.f - e) / (1.f + e);
  return copysignf(r, v);
}
__device__ __forceinline__ unsigned long long pack4(const unsigned short* v) {
  return (unsigned long long)v[0] | ((unsigned long long)v[1] << 16) |
         ((unsigned long long)v[2] << 32) | ((unsigned long long)v[3] << 48);
}

#define ALD(p) __hip_atomic_load((p), __ATOMIC_RELAXED, __HIP_MEMORY_SCOPE_AGENT)
#define AST(p, v) __hip_atomic_store((p), (v), __ATOMIC_RELAXED, __HIP_MEMORY_SCOPE_AGENT)

// ---------------------------------------------------------------------------
// Prologue: sample W = mu + softplus(rho)*eps for [w_hh; w_ih; 0pad] (608x2048)
// and pack into MFMA B-fragment chunks.
// ---------------------------------------------------------------------------
__global__ __launch_bounds__(64) void pack_w_kernel(
    const float* __restrict__ wih_mu, const float* __restrict__ wih_rho, const float* __restrict__ eps_ih,
    const float* __restrict__ whh_mu, const float* __restrict__ whh_rho, const float* __restrict__ eps_hh,
    unsigned short* __restrict__ wpack)
{
  int c = blockIdx.x;             // 0..2431
  int j = c / (8 * NKK);
  int r = c % (8 * NKK);
  int wv = r / NKK;
  int kk = r % NKK;
  int l = threadIdx.x;
  int s = l & 15, grp = l >> 4;
  int q = s >> 2, cc = s & 3;
  int n = q * 512 + j * 32 + wv * 4 + cc;
  unsigned short vs[8];
#pragma unroll
  for (int e = 0; e < 8; ++e) {
    int k = kk * 32 + grp * 8 + e;
    float val = 0.f;
    if (k < 512) {
      int idx = k * G_DIM + n;
      val = whh_mu[idx] + softplusf(whh_rho[idx]) * eps_hh[idx];
    } else if (k < 512 + D_IN) {
      int idx = (k - 512) * G_DIM + n;
      val = wih_mu[idx] + softplusf(wih_rho[idx]) * eps_ih[idx];
    }
    vs[e] = f2b(val);
  }
  unsigned long long u0 = pack4(vs);
  unsigned long long u1 = pack4(vs + 4);
  unsigned long long* dst = (unsigned long long*)wpack + (size_t)c * 128 + l * 2;
  dst[0] = u0;
  dst[1] = u1;
}

// ---------------------------------------------------------------------------
// Persistent scan kernel. 128 blocks; g=bid&7 (XCD-clustered for x/L2 locality
// — a perf heuristic only, correctness never depends on it), j=bid>>3.
// ALL cross-block data/flag traffic: __hip_atomic_* AGENT (sc1) — the round-3
// proven semantics. No sc0-only ops (rounds 4/5 deadlock: sc0 alone does not
// bypass the non-coherent L1; agent=sc1, system=sc0 sc1).
// Per-wave flags on private 64B lines; per-wave publish; ONE barrier/step.
// Ordering argument (all verified):
//  - flag_w >= t+2  ==>  wave w finished iter-t MFMA (hstage/x_lds reads) and
//    its hbuf[t&1] staging reads. So a wave entering iter t+1 (poll passed for
//    ALL 64 waves incl. own block) may overwrite hstage / x_lds[(t+2)&1] /
//    hbuf[(t+2)&1] safely.
//  - publish stores are acked (vmcnt(0)) before the flag store issues, both at
//    agent scope -> any consumer seeing flag>=t+2 sees h_{t+1}.
// Staging: all 16 ULL loads issued back-to-back into regs (relaxed atomics,
// no intervening uses -> ONE vmcnt drain, not 8 serialized LLC round-trips,
// which was ~3us/step of round 3's 7.7). Wave1's x-commit VALU work sits in
// the load-latency window.
// ---------------------------------------------------------------------------
struct SmemLoop {
  unsigned short hstage[32][64][8];   // 32KB  staged h chunks, A-frag layout
  float gatesT[4][2][2][16][20];      // 20KB  [wave][ct][rg][slotN][rowM pad20]
  unsigned short hq[4][2][16][24];    // 6KB   per-wave h quarter, rows padded 48B
  unsigned short x_lds[2][6][64][8];  // 12KB  [buf][rg*3+kx][lane][e]
};
union Smem {
  SmemLoop s;
  unsigned short zbuf[32][512];       // 32KB (post-loop only)
};

__global__ __launch_bounds__(256, 1) void lstm_scan_kernel(
    const float* __restrict__ x,
    const unsigned short* __restrict__ wpack,
    const float* __restrict__ b_mu, const float* __restrict__ b_rho, const float* __restrict__ eps_b,
    const float* __restrict__ fc_w, const float* __restrict__ fc_b,
    unsigned long long* __restrict__ hbuf, int* __restrict__ flags,
    float* __restrict__ out)
{
  __shared__ Smem sm;

  const int bid = blockIdx.x;
  const int g = bid & 7, j = bid >> 3;      // XCD-clustered groups
  const int tid = threadIdx.x;
  const int w = tid >> 6, lane = tid & 63;
  const int srow = lane & 15, grp = lane >> 4;

  // ---- load stationary W fragments (2 col-tiles x 19 ktiles x 16B per lane)
  short8 Wreg[2][NKK];
  {
    const short8* wp = (const short8*)wpack;
#pragma unroll
    for (int ct = 0; ct < 2; ++ct) {
      const int cj = (j * 8 + w * 2 + ct) * NKK;
#pragma unroll
      for (int kk = 0; kk < NKK; ++kk)
        Wreg[ct][kk] = wp[(size_t)(cj + kk) * 64 + lane];
    }
  }
  // ---- sampled bias (epilogue lane role: row=srow, cc=grp)
  float bias_[2][4];
#pragma unroll
  for (int ct = 0; ct < 2; ++ct)
#pragma unroll
    for (int q = 0; q < 4; ++q) {
      int idx = q * 512 + j * 32 + (w * 2 + ct) * 4 + grp;
      bias_[ct][q] = b_mu[idx] + softplusf(b_rho[idx]) * eps_b[idx];
    }

  float cst[2][2] = {{0.f, 0.f}, {0.f, 0.f}};
  int* const myflag = &flags[((g * 16 + j) * 4 + w) * 16];

  // ---- wave1: fill x_0 and x_1 into LDS (before the h0 flag publish)
  float xv[2][3][8];
  if (w == 1) {
#pragma unroll
    for (int tt = 0; tt < 2; ++tt) {
#pragma unroll
      for (int rg = 0; rg < 2; ++rg) {
        const float* xr = x + (size_t)(g * 32 + rg * 16 + srow) * (T_STEPS * D_IN) + (size_t)tt * D_IN;
#pragma unroll
        for (int kx = 0; kx < 3; ++kx) {
          int d0 = kx * 32 + grp * 8;
          unsigned short vs[8];
#pragma unroll
          for (int e = 0; e < 8; ++e) {
            int d = d0 + e;
            vs[e] = f2b(d < D_IN ? xr[d] : 0.f);
          }
          unsigned long long* dp = (unsigned long long*)&sm.s.x_lds[tt][rg * 3 + kx][lane][0];
          dp[0] = pack4(vs);
          dp[1] = pack4(vs + 4);
        }
      }
    }
  }

  // ---- publish h_0 = 0 (each wave publishes its quarter: chunk positions
  //      (grp=w, srow=row) of chunks rg*16+j), then flag=1
  {
    unsigned long long* hb0 = hbuf + (size_t)(0 * NG + g) * 4096;
    if (lane < 32) {
      int rg = lane >> 4, row = lane & 15;
      unsigned long long* dst = hb0 + (size_t)((rg * 16 + j) * 64 + (w * 16 + row)) * 2;
      AST(dst, 0ull);
      AST(dst + 1, 0ull);
    }
    asm volatile("s_waitcnt vmcnt(0)" ::: "memory");
    if (lane == 0) AST(myflag, 1);
  }

  for (int t = 0; t < T_STEPS; ++t) {
    // ---- poll all 64 producer-wave flags of group g (lane -> (j',w'))
    {
      const int tgt = t + 1;
      const int* fp = &flags[((g * 16 + (lane & 15)) * 4 + (lane >> 4)) * 16];
      while (true) {
        int f = ALD(fp);
        if (__all(f >= tgt)) break;
        __builtin_amdgcn_s_sleep(1);
      }
    }

    // ---- stage this wave's 8 chunks: issue ALL 16 loads into regs first
    const unsigned long long* hb = hbuf + (size_t)((t & 1) * NG + g) * 4096;
    unsigned long long sv[16];
#pragma unroll
    for (int c8 = 0; c8 < 8; ++c8) {
      const unsigned long long* p = hb + (size_t)(w * 8 + c8) * 128 + lane * 2;
      sv[2 * c8]     = ALD(p);
      sv[2 * c8 + 1] = ALD(p + 1);
    }

    // ---- wave1: commit x_{t+1} (regs loaded at end of iter t-1) to LDS —
    //      VALU work overlapping the staged-load latency
    if (w == 1 && t >= 1 && t + 1 < T_STEPS) {
      const int buf = (t + 1) & 1;
#pragma unroll
      for (int rg = 0; rg < 2; ++rg)
#pragma unroll
        for (int kx = 0; kx < 3; ++kx) {
          unsigned short vs[8];
#pragma unroll
          for (int e = 0; e < 8; ++e) vs[e] = f2b(xv[rg][kx][e]);
          unsigned long long* dp = (unsigned long long*)&sm.s.x_lds[buf][rg * 3 + kx][lane][0];
          dp[0] = pack4(vs);
          dp[1] = pack4(vs + 4);
        }
    }

    // ---- regs -> LDS hstage (single vmcnt drain happens here)
#pragma unroll
    for (int c8 = 0; c8 < 8; ++c8) {
      unsigned long long* dp = (unsigned long long*)&sm.s.hstage[w * 8 + c8][lane][0];
      dp[0] = sv[2 * c8];
      dp[1] = sv[2 * c8 + 1];
    }

    __syncthreads();   // the ONE barrier per step

    // ---- MFMA: x tiles then h tiles
    f32x4 acc[2][2];
#pragma unroll
    for (int ct = 0; ct < 2; ++ct)
#pragma unroll
      for (int rg = 0; rg < 2; ++rg)
        acc[ct][rg] = (f32x4){0.f, 0.f, 0.f, 0.f};

#pragma unroll
    for (int kx = 0; kx < 3; ++kx) {
      short8 a0 = *(const short8*)&sm.s.x_lds[t & 1][kx][lane][0];      // rg0
      short8 a1 = *(const short8*)&sm.s.x_lds[t & 1][3 + kx][lane][0];  // rg1
      acc[0][0] = __builtin_amdgcn_mfma_f32_16x16x32_bf16(a0, Wreg[0][16 + kx], acc[0][0], 0, 0, 0);
      acc[1][0] = __builtin_amdgcn_mfma_f32_16x16x32_bf16(a0, Wreg[1][16 + kx], acc[1][0], 0, 0, 0);
      acc[0][1] = __builtin_amdgcn_mfma_f32_16x16x32_bf16(a1, Wreg[0][16 + kx], acc[0][1], 0, 0, 0);
      acc[1][1] = __builtin_amdgcn_mfma_f32_16x16x32_bf16(a1, Wreg[1][16 + kx], acc[1][1], 0, 0, 0);
    }
#pragma unroll
    for (int kk = 0; kk < 16; ++kk) {
      short8 a0 = *(const short8*)&sm.s.hstage[kk][lane][0];       // rg0
      short8 a1 = *(const short8*)&sm.s.hstage[16 + kk][lane][0];  // rg1
      acc[0][0] = __builtin_amdgcn_mfma_f32_16x16x32_bf16(a0, Wreg[0][kk], acc[0][0], 0, 0, 0);
      acc[1][0] = __builtin_amdgcn_mfma_f32_16x16x32_bf16(a0, Wreg[1][kk], acc[1][0], 0, 0, 0);
      acc[0][1] = __builtin_amdgcn_mfma_f32_16x16x32_bf16(a1, Wreg[0][kk], acc[0][1], 0, 0, 0);
      acc[1][1] = __builtin_amdgcn_mfma_f32_16x16x32_bf16(a1, Wreg[1][kk], acc[1][1], 0, 0, 0);
    }

    // ---- epilogue: transpose gates within wave, activations, update c,h
#pragma unroll
    for (int ct = 0; ct < 2; ++ct) {
      *(f32x4*)&sm.s.gatesT[w][ct][0][srow][grp * 4] = acc[ct][0];
      *(f32x4*)&sm.s.gatesT[w][ct][1][srow][grp * 4] = acc[ct][1];
    }
#pragma unroll
    for (int ct = 0; ct < 2; ++ct)
#pragma unroll
      for (int rg = 0; rg < 2; ++rg) {
        float vi = sm.s.gatesT[w][ct][rg][grp + 0][srow] + bias_[ct][0];
        float vf = sm.s.gatesT[w][ct][rg][grp + 4][srow] + bias_[ct][1];
        float vg = sm.s.gatesT[w][ct][rg][grp + 8][srow] + bias_[ct][2];
        float vo = sm.s.gatesT[w][ct][rg][grp + 12][srow] + bias_[ct][3];
        float ii = sigmf(vi), ff = sigmf(vf);
        float gg = tanhf_(vg), oo = sigmf(vo);
        float cn = ff * cst[ct][rg] + ii * gg;
        cst[ct][rg] = cn;
        float hh = oo * tanhf_(cn);
        sm.s.hq[w][rg][srow][ct * 4 + grp] = f2b(hh);
      }

    // ---- per-wave publish of h_{t+1} quarter + own flag (no barrier needed:
    //      consumers gate on ALL 64 flags, which implies all prior reads done)
    {
      unsigned long long* hbn = hbuf + (size_t)(((t + 1) & 1) * NG + g) * 4096;
      if (lane < 32) {
        int rg = lane >> 4, row = lane & 15;
        const unsigned long long* hp = (const unsigned long long*)&sm.s.hq[w][rg][row][0];
        unsigned long long u0 = hp[0], u1 = hp[1];
        unsigned long long* dst = hbn + (size_t)((rg * 16 + j) * 64 + (w * 16 + row)) * 2;
        AST(dst, u0);
        AST(dst + 1, u1);
      }
      asm volatile("s_waitcnt vmcnt(0)" ::: "memory");
      if (lane == 0) AST(myflag, t + 2);
    }

    // ---- wave1: issue x_{t+2} loads (land during next step's poll/stage)
    if (w == 1 && t + 2 < T_STEPS) {
      const int tn = t + 2;
#pragma unroll
      for (int rg = 0; rg < 2; ++rg) {
        const float* xr = x + (size_t)(g * 32 + rg * 16 + srow) * (T_STEPS * D_IN) + (size_t)tn * D_IN;
#pragma unroll
        for (int kx = 0; kx < 3; ++kx) {
          int d0 = kx * 32 + grp * 8;
#pragma unroll
          for (int e = 0; e < 8; ++e) {
            int d = d0 + e;
            xv[rg][kx][e] = (d < D_IN) ? xr[d] : 0.f;
          }
        }
      }
    }
  }

  // ---- final FC: z = h_T @ fc_w^T + fc_b  (j==0 blocks; h_512 is in hbuf[0])
  if (j == 0) {
    {
      const int tgt = T_STEPS + 1;
      const int* fp = &flags[((g * 16 + (lane & 15)) * 4 + (lane >> 4)) * 16];
      while (true) {
        int f = ALD(fp);
        if (__all(f >= tgt)) break;
        __builtin_amdgcn_s_sleep(1);
      }
    }
    __syncthreads();   // all waves past the loop before zbuf overwrites the union
    const unsigned long long* hb0 = hbuf + (size_t)(0 * NG + g) * 4096;
    for (int it = tid; it < 2048; it += 256) {
      unsigned long long a = ALD(hb0 + it * 2);
      unsigned long long b = ALD(hb0 + it * 2 + 1);
      ((unsigned long long*)sm.zbuf)[it * 2] = a;
      ((unsigned long long*)sm.zbuf)[it * 2 + 1] = b;
    }
    __syncthreads();
    for (int i = tid; i < 32 * NCLS_; i += 256) {
      int r = i / NCLS_, n = i % NCLS_;
      float s = fc_b[n];
      const float* fw = fc_w + n * H_DIM;
      int rg = r >> 4, rr = r & 15;
      for (int k = 0; k < H_DIM; ++k) {
        int kk = k >> 5, lch = rr + (((k >> 3) & 3) << 4), e = k & 7;
        unsigned short hu = ((const unsigned short*)sm.zbuf)[(((rg * 16 + kk) * 64 + lch) << 3) + e];
        s += b2f(hu) * fw[k];
      }
      out[(g * 32 + r) * NCLS_ + n] = s;
    }
  }
}

// ---------------------------------------------------------------------------
extern "C" void kernel_launch(void* const* d_in, const int* in_sizes, int n_in,
                              void* d_out, int out_size, void* d_ws, size_t ws_size,
                              hipStream_t stream) {
  const float* x       = (const float*)d_in[0];
  const float* wih_mu  = (const float*)d_in[1];
  const float* wih_rho = (const float*)d_in[2];
  const float* eps_ih  = (const float*)d_in[3];
  const float* whh_mu  = (const float*)d_in[4];
  const float* whh_rho = (const float*)d_in[5];
  const float* eps_hh  = (const float*)d_in[6];
  const float* b_mu    = (const float*)d_in[7];
  const float* b_rho   = (const float*)d_in[8];
  const float* eps_b   = (const float*)d_in[9];
  const float* fc_w    = (const float*)d_in[10];
  const float* fc_b    = (const float*)d_in[11];

  // ws layout: wpack [0, 2490368) | hbuf [2490368, 3014656) | flags [3014656, +32768)
  unsigned short* wpack = (unsigned short*)d_ws;
  unsigned long long* hbuf = (unsigned long long*)((char*)d_ws + 2490368);
  int* flags = (int*)((char*)d_ws + 3014656);

  hipMemsetAsync(flags, 0, 32768, stream);
  pack_w_kernel<<<NJ * 8 * NKK, 64, 0, stream>>>(wih_mu, wih_rho, eps_ih,
                                                 whh_mu, whh_rho, eps_hh, wpack);
  lstm_scan_kernel<<<NG * NJ, 256, 0, stream>>>(x, wpack, b_mu, b_rho, eps_b,
                                                fc_w, fc_b, hbuf, flags,
                                                (float*)d_out);
}